// Round 1
// baseline (1671.584 us; speedup 1.0000x reference)
//
#include <hip/hip_runtime.h>

// Orthonorm: Y = X * (sqrt(512) * inv(chol(X^T X + eps I))^T)
// X: [262144, 512] fp32.  All heavy matmuls via bf16 MFMA (fp32 accum).

#define EPSJ 1e-6f
#define SQRTD 22.627416997969522f

typedef short bf16x8 __attribute__((ext_vector_type(8)));
typedef float f32x4 __attribute__((ext_vector_type(4)));

__device__ __forceinline__ unsigned short f2bf(float f) {
  unsigned u = __float_as_uint(f);
  unsigned r = u + 0x7fffu + ((u >> 16) & 1u);   // RNE
  return (unsigned short)(r >> 16);
}

// 16B-slot XOR swizzle within a 128B LDS row (8 slots)
__device__ __forceinline__ int swz(int row, int slot) {
  return slot ^ ((row ^ (row >> 3)) & 7);
}

__device__ __forceinline__ float wred(float s) {
  s += __shfl_xor(s, 1);  s += __shfl_xor(s, 2);  s += __shfl_xor(s, 4);
  s += __shfl_xor(s, 8);  s += __shfl_xor(s, 16); s += __shfl_xor(s, 32);
  return s;
}

// ---------------------------------------------------------------------------
// Kernel 1: Gram partials. grid = 3*nchunk blocks x 512 thr.
// pos = b%3: (0,0),(256,256),(0,256) 256x256 tiles of G; chunk = b/3 K-slice.
// LDS tiles are [c][k] (K-innermost, 128B rows, swizzled) built by transposed
// scatter writes during fp32->bf16 staging.
// ---------------------------------------------------------------------------
__global__ __launch_bounds__(512, 2) void gram_partial(
    const float* __restrict__ X, float* __restrict__ part, int nchunk) {
  __shared__ unsigned short As[256 * 64];
  __shared__ unsigned short Bs[256 * 64];
  const int b = blockIdx.x;
  const int pos = b % 3;
  const int chunk = b / 3;
  const int CR = 262144 / nchunk;
  const long r0 = (long)chunk * CR;
  const int ca = (pos == 1) ? 256 : 0;
  const int cb = (pos == 0) ? 0 : 256;
  const bool diag = (pos != 2);
  const int t = threadIdx.x, lane = t & 63, w = t >> 6;
  const int wr = w >> 2, wc = w & 3;   // wave tile: rows wr*128, cols wc*64

  f32x4 acc[8][4];
  const f32x4 zf = {0.f, 0.f, 0.f, 0.f};
  #pragma unroll
  for (int a = 0; a < 8; ++a)
    #pragma unroll
    for (int bb = 0; bb < 4; ++bb) acc[a][bb] = zf;

  const int c_oct = t & 31, msub = t >> 5;

  for (int ks = 0; ks < CR; ks += 64) {
    #pragma unroll
    for (int it = 0; it < 4; ++it) {
      int m = msub + 16 * it;
      long row = r0 + ks + m;
      const float4* sa = (const float4*)(X + row * 512 + ca + c_oct * 8);
      float4 a0 = sa[0], a1 = sa[1];
      {
        float v[8] = {a0.x, a0.y, a0.z, a0.w, a1.x, a1.y, a1.z, a1.w};
        #pragma unroll
        for (int s = 0; s < 8; ++s) {
          int c = c_oct * 8 + s;
          int off = c * 128 + ((2 * m) ^ (((c ^ (c >> 3)) & 7) << 4));
          *(unsigned short*)((char*)As + off) = f2bf(v[s]);
        }
      }
      if (!diag) {
        const float4* sb = (const float4*)(X + row * 512 + cb + c_oct * 8);
        float4 b0 = sb[0], b1 = sb[1];
        float v[8] = {b0.x, b0.y, b0.z, b0.w, b1.x, b1.y, b1.z, b1.w};
        #pragma unroll
        for (int s = 0; s < 8; ++s) {
          int c = c_oct * 8 + s;
          int off = c * 128 + ((2 * m) ^ (((c ^ (c >> 3)) & 7) << 4));
          *(unsigned short*)((char*)Bs + off) = f2bf(v[s]);
        }
      }
    }
    __syncthreads();
    const unsigned short* Bp = diag ? As : Bs;
    #pragma unroll
    for (int kk = 0; kk < 2; ++kk) {
      bf16x8 af[8], bfr[4];
      #pragma unroll
      for (int fm = 0; fm < 8; ++fm) {
        int row = wr * 128 + fm * 16 + (lane & 15);
        int slot = swz(row, kk * 4 + (lane >> 4));
        af[fm] = *(const bf16x8*)((const char*)As + row * 128 + slot * 16);
      }
      #pragma unroll
      for (int fn = 0; fn < 4; ++fn) {
        int row = wc * 64 + fn * 16 + (lane & 15);
        int slot = swz(row, kk * 4 + (lane >> 4));
        bfr[fn] = *(const bf16x8*)((const char*)Bp + row * 128 + slot * 16);
      }
      #pragma unroll
      for (int fm = 0; fm < 8; ++fm)
        #pragma unroll
        for (int fn = 0; fn < 4; ++fn)
          acc[fm][fn] = __builtin_amdgcn_mfma_f32_16x16x32_bf16(
              af[fm], bfr[fn], acc[fm][fn], 0, 0, 0);
    }
    __syncthreads();
  }
  float* out = part + (long)b * 65536;
  #pragma unroll
  for (int fm = 0; fm < 8; ++fm)
    #pragma unroll
    for (int fn = 0; fn < 4; ++fn)
      #pragma unroll
      for (int j = 0; j < 4; ++j) {
        int i  = wr * 128 + fm * 16 + (lane >> 4) * 4 + j;
        int jj = wc * 64 + fn * 16 + (lane & 15);
        out[i * 256 + jj] = acc[fm][fn][j];
      }
}

// ---------------------------------------------------------------------------
// Kernel 2: reduce partials -> full symmetric G [512][512] fp32
// grid = 768 x 256
// ---------------------------------------------------------------------------
__global__ void gram_reduce(const float* __restrict__ part,
                            float* __restrict__ G, int nchunk) {
  int idx = blockIdx.x * 256 + threadIdx.x;   // < 196608
  int pos = idx >> 16;
  int e = idx & 65535;
  float s = 0.f;
  for (int ch = 0; ch < nchunk; ++ch)
    s += part[(long)(ch * 3 + pos) * 65536 + e];
  int i = e >> 8, j = e & 255;
  if (pos == 0) {
    G[i * 512 + j] = s;
  } else if (pos == 1) {
    G[(256 + i) * 512 + 256 + j] = s;
  } else {
    G[i * 512 + 256 + j] = s;
    G[(256 + j) * 512 + i] = s;
  }
}

// ---------------------------------------------------------------------------
// Kernel 3: factor 128x128 diagonal block at (c0,c0) of G in place (lower L).
// Single block, 512 thr. 32-col sub-panels: wave0 register factor (shfl),
// thread-per-row solve below, block-parallel rank-32 update.
// ---------------------------------------------------------------------------
__global__ void chol_diag(float* __restrict__ G, int c0) {
  __shared__ float P[128][129];
  int t = threadIdx.x;
  for (int idx = t; idx < 128 * 128; idx += 512) {
    int i = idx >> 7, j = idx & 127;
    float v = G[(long)(c0 + i) * 512 + c0 + j];
    if (i == j) v += EPSJ;
    P[i][j] = v;
  }
  __syncthreads();
  int lane = t & 63, w = t >> 6;
  for (int sp = 0; sp < 4; ++sp) {
    int b0 = sp * 32;
    if (w == 0) {
      float r[32];
      #pragma unroll
      for (int k = 0; k < 32; ++k) r[k] = (lane < 32) ? P[b0 + lane][b0 + k] : 0.f;
      #pragma unroll
      for (int j = 0; j < 32; ++j) {
        float d = sqrtf(__shfl(r[j], j));
        if (lane == j) r[j] = d;
        else if (lane > j && lane < 32) r[j] = r[j] / d;
        float rj = r[j];
        #pragma unroll
        for (int k = j + 1; k < 32; ++k) {
          float Lkj = __shfl(rj, k);
          if (lane > j && lane < 32) r[k] -= rj * Lkj;
        }
      }
      #pragma unroll
      for (int k = 0; k < 32; ++k) if (lane < 32) P[b0 + lane][b0 + k] = r[k];
    }
    __syncthreads();
    int nb = 128 - (b0 + 32);
    if (nb > 0) {
      if (t < nb) {
        int rr = b0 + 32 + t;
        float x[32];
        #pragma unroll
        for (int j = 0; j < 32; ++j) x[j] = P[rr][b0 + j];
        #pragma unroll
        for (int j = 0; j < 32; ++j) {
          float xj = x[j] / P[b0 + j][b0 + j];
          x[j] = xj;
          #pragma unroll
          for (int k2 = j + 1; k2 < 32; ++k2) x[k2] -= xj * P[b0 + k2][b0 + j];
        }
        #pragma unroll
        for (int j = 0; j < 32; ++j) P[rr][b0 + j] = x[j];
      }
      __syncthreads();
      int total = nb * nb;
      for (int idx = t; idx < total; idx += 512) {
        int i = b0 + 32 + idx / nb, k = b0 + 32 + idx % nb;
        float s = P[i][k];
        #pragma unroll
        for (int j = 0; j < 32; ++j) s -= P[i][b0 + j] * P[k][b0 + j];
        P[i][k] = s;
      }
      __syncthreads();
    }
  }
  for (int idx = t; idx < 128 * 128; idx += 512) {
    int i = idx >> 7, j = idx & 127;
    G[(long)(c0 + i) * 512 + c0 + j] = P[i][j];
  }
}

// ---------------------------------------------------------------------------
// Kernel 4: panel solve. L21 rows = A21 * L11^{-T}, wave-per-row forward
// substitution against the 128x128 diag block at (c0,c0). grid = R/4 x 256.
// ---------------------------------------------------------------------------
__global__ void chol_solve(float* __restrict__ G, int p) {
  int c0 = 128 * p;
  int row0 = c0 + 128;
  int w = threadIdx.x >> 6, lane = threadIdx.x & 63;
  long r = row0 + blockIdx.x * 4 + w;
  float x[2];
  x[0] = G[r * 512 + c0 + lane];
  x[1] = G[r * 512 + c0 + 64 + lane];
  #pragma unroll
  for (int q = 0; q < 2; ++q) {
    for (int ii = 0; ii < 64; ++ii) {
      int i = q * 64 + ii;
      const float* Lrow = G + (long)(c0 + i) * 512 + c0;
      float s = 0.f;
      if (q == 1) s += x[0] * Lrow[lane];
      s += (lane < ii) ? x[q] * Lrow[q * 64 + lane] : 0.f;
      s = wred(s);
      float ai = __shfl(x[q], ii);
      float xi = (ai - s) / Lrow[i];
      if (lane == ii) x[q] = xi;
    }
  }
  G[r * 512 + c0 + lane] = x[0];
  G[r * 512 + c0 + 64 + lane] = x[1];
}

// ---------------------------------------------------------------------------
// Kernel 5: SYRK trailing update A22 -= L21 L21^T, 64x64 lower tiles, fp32.
// grid = nt(nt+1)/2 x 256 where nt = (512-t0)/64.
// ---------------------------------------------------------------------------
__global__ void chol_syrk(float* __restrict__ G, int t0) {
  int id = blockIdx.x;
  int ti = 0;
  while ((ti + 1) * (ti + 2) / 2 <= id) ++ti;
  int tj = id - ti * (ti + 1) / 2;
  __shared__ float As2[64][130], Bs2[64][130];
  int t = threadIdx.x;
  int c0 = t0 - 128;
  for (int idx = t; idx < 64 * 128; idx += 256) {
    int i = idx >> 7, j = idx & 127;
    As2[i][j] = G[(long)(t0 + 64 * ti + i) * 512 + c0 + j];
    Bs2[i][j] = G[(long)(t0 + 64 * tj + i) * 512 + c0 + j];
  }
  __syncthreads();
  int tr = (t >> 4) * 4, tc = (t & 15) * 4;
  float cacc[4][4];
  #pragma unroll
  for (int u = 0; u < 4; ++u)
    #pragma unroll
    for (int v = 0; v < 4; ++v) cacc[u][v] = 0.f;
  for (int k = 0; k < 128; ++k) {
    float a4[4], b4[4];
    #pragma unroll
    for (int u = 0; u < 4; ++u) { a4[u] = As2[tr + u][k]; b4[u] = Bs2[tc + u][k]; }
    #pragma unroll
    for (int u = 0; u < 4; ++u)
      #pragma unroll
      for (int v = 0; v < 4; ++v) cacc[u][v] += a4[u] * b4[v];
  }
  #pragma unroll
  for (int u = 0; u < 4; ++u)
    #pragma unroll
    for (int v = 0; v < 4; ++v)
      G[(long)(t0 + 64 * ti + tr + u) * 512 + t0 + 64 * tj + tc + v] -= cacc[u][v];
}

// ---------------------------------------------------------------------------
// Kernel 6: triangular inverse, wave-per-column: L v = e_c.  Writes
// Wt[n][k] = sqrt(512)*V[n][k] in bf16 (B^T layout for the Y GEMM).
// grid = 128 x 256 (512 waves = 512 columns).
// ---------------------------------------------------------------------------
__global__ void tri_inv(const float* __restrict__ G,
                        unsigned short* __restrict__ Wt) {
  int w = threadIdx.x >> 6, lane = threadIdx.x & 63;
  int c = blockIdx.x * 4 + w;
  float v8[8];
  #pragma unroll
  for (int q = 0; q < 8; ++q) v8[q] = 0.f;
  #pragma unroll
  for (int q = 0; q < 8; ++q) {
    for (int ii = 0; ii < 64; ++ii) {
      int i = q * 64 + ii;
      const float* Lrow = G + (long)i * 512;
      float s = 0.f;
      #pragma unroll
      for (int qq = 0; qq < 8; ++qq) {
        if (qq < q) s += v8[qq] * Lrow[qq * 64 + lane];
      }
      s += (lane < ii) ? v8[q] * Lrow[q * 64 + lane] : 0.f;
      s = wred(s);
      float xi = (((i == c) ? 1.f : 0.f) - s) / Lrow[i];
      if (lane == ii) v8[q] = xi;
    }
  }
  #pragma unroll
  for (int q = 0; q < 8; ++q) {
    int i = q * 64 + lane;
    Wt[(long)i * 512 + c] = f2bf(SQRTD * v8[q]);
  }
}

// ---------------------------------------------------------------------------
// Kernel 7: Y = Xbf16 @ W.  128x128 tiles, BK=64, 4 waves.
// A: fp32->bf16 reg-staged (K contiguous -> clean b128 writes).
// B: bf16 Wt rows (B^T layout) -> b128 staged. Both swizzled.
// grid = (2048, 4) x 256.
// ---------------------------------------------------------------------------
__global__ __launch_bounds__(256) void ymm(const float* __restrict__ X,
                                           const unsigned short* __restrict__ Wt,
                                           float* __restrict__ Y) {
  __shared__ unsigned short As[128 * 64];
  __shared__ unsigned short Bs[128 * 64];
  const int t = threadIdx.x, lane = t & 63, w = t >> 6;
  const long m0 = (long)blockIdx.x * 128;
  const int n0 = blockIdx.y * 128;
  const int wm = (w >> 1) * 64, wn = (w & 1) * 64;
  f32x4 acc[4][4];
  const f32x4 zf = {0.f, 0.f, 0.f, 0.f};
  #pragma unroll
  for (int a = 0; a < 4; ++a)
    #pragma unroll
    for (int bq = 0; bq < 4; ++bq) acc[a][bq] = zf;
  const int ko = t & 7, mrow = t >> 3;   // 8 k-octets x 32 rows

  for (int k0 = 0; k0 < 512; k0 += 64) {
    #pragma unroll
    for (int it = 0; it < 4; ++it) {
      int m = mrow + 32 * it;
      const float4* src = (const float4*)(X + (m0 + m) * 512 + k0 + ko * 8);
      float4 f0 = src[0], f1 = src[1];
      unsigned p0 = (unsigned)f2bf(f0.x) | ((unsigned)f2bf(f0.y) << 16);
      unsigned p1 = (unsigned)f2bf(f0.z) | ((unsigned)f2bf(f0.w) << 16);
      unsigned p2 = (unsigned)f2bf(f1.x) | ((unsigned)f2bf(f1.y) << 16);
      unsigned p3 = (unsigned)f2bf(f1.z) | ((unsigned)f2bf(f1.w) << 16);
      int slot = swz(m, ko);
      *(uint4*)((char*)As + m * 128 + slot * 16) = make_uint4(p0, p1, p2, p3);
    }
    #pragma unroll
    for (int it = 0; it < 4; ++it) {
      int n = mrow + 32 * it;
      uint4 raw = *(const uint4*)(Wt + (long)(n0 + n) * 512 + k0 + ko * 8);
      int slot = swz(n, ko);
      *(uint4*)((char*)Bs + n * 128 + slot * 16) = raw;
    }
    __syncthreads();
    #pragma unroll
    for (int kk = 0; kk < 2; ++kk) {
      bf16x8 af[4], bfr[4];
      #pragma unroll
      for (int fm = 0; fm < 4; ++fm) {
        int row = wm + fm * 16 + (lane & 15);
        af[fm] = *(const bf16x8*)((const char*)As + row * 128 +
                                  swz(row, kk * 4 + (lane >> 4)) * 16);
      }
      #pragma unroll
      for (int fn = 0; fn < 4; ++fn) {
        int row = wn + fn * 16 + (lane & 15);
        bfr[fn] = *(const bf16x8*)((const char*)Bs + row * 128 +
                                   swz(row, kk * 4 + (lane >> 4)) * 16);
      }
      #pragma unroll
      for (int fm = 0; fm < 4; ++fm)
        #pragma unroll
        for (int fn = 0; fn < 4; ++fn)
          acc[fm][fn] = __builtin_amdgcn_mfma_f32_16x16x32_bf16(
              af[fm], bfr[fn], acc[fm][fn], 0, 0, 0);
    }
    __syncthreads();
  }
  #pragma unroll
  for (int fm = 0; fm < 4; ++fm)
    #pragma unroll
    for (int fn = 0; fn < 4; ++fn)
      #pragma unroll
      for (int j = 0; j < 4; ++j) {
        long row = m0 + wm + fm * 16 + (lane >> 4) * 4 + j;
        int col = n0 + wn + fn * 16 + (lane & 15);
        Y[row * 512 + col] = acc[fm][fn][j];
      }
}

// ---------------------------------------------------------------------------
extern "C" void kernel_launch(void* const* d_in, const int* in_sizes, int n_in,
                              void* d_out, int out_size, void* d_ws, size_t ws_size,
                              hipStream_t stream) {
  const float* X = (const float*)d_in[0];
  float* Y = (float*)d_out;
  char* ws = (char*)d_ws;
  float* G = (float*)ws;                                     // 1 MB fp32
  unsigned short* Wt = (unsigned short*)(ws + (1 << 20));    // 512 KB bf16
  float* part = (float*)(ws + (1 << 20) + (1 << 19));        // partials
  size_t fixed = (size_t)(1 << 20) + (1 << 19);
  int nchunk = 64;
  while (nchunk > 1 && fixed + (size_t)nchunk * 3 * 65536 * 4 > ws_size)
    nchunk >>= 1;

  gram_partial<<<3 * nchunk, 512, 0, stream>>>(X, part, nchunk);
  gram_reduce<<<768, 256, 0, stream>>>(part, G, nchunk);
  for (int p = 0; p < 4; ++p) {
    chol_diag<<<1, 512, 0, stream>>>(G, 128 * p);
    if (p < 3) {
      int row0 = 128 * (p + 1);
      chol_solve<<<(512 - row0) / 4, 256, 0, stream>>>(G, p);
      int nt = (512 - row0) / 64;
      chol_syrk<<<nt * (nt + 1) / 2, 256, 0, stream>>>(G, row0);
    }
  }
  tri_inv<<<128, 256, 0, stream>>>(G, Wt);
  ymm<<<dim3(2048, 4), 256, 0, stream>>>(X, Wt, Y);
}

// Round 2
// 1463.863 us; speedup vs baseline: 1.1419x; 1.1419x over previous
//
#include <hip/hip_runtime.h>

// Orthonorm: Y = X * (sqrt(512) * inv(chol(X^T X + eps I))^T)
// X: [262144, 512] fp32.  All heavy matmuls via bf16 MFMA (fp32 accum).
// Fast path: X converted to bf16 once (ws-resident), gram + ymm read bf16,
// ymm stages via global_load_lds with pre-swizzled sources.

#define EPSJ 1e-6f
#define SQRTD 22.627416997969522f

typedef short bf16x8 __attribute__((ext_vector_type(8)));
typedef float f32x4 __attribute__((ext_vector_type(4)));

__device__ __forceinline__ unsigned short f2bf(float f) {
  unsigned u = __float_as_uint(f);
  unsigned r = u + 0x7fffu + ((u >> 16) & 1u);   // RNE
  return (unsigned short)(r >> 16);
}

// 16B-slot XOR swizzle within a 128B LDS row (8 slots). Involution in slot.
__device__ __forceinline__ int swz(int row, int slot) {
  return slot ^ ((row ^ (row >> 3)) & 7);
}

__device__ __forceinline__ float wred(float s) {
  s += __shfl_xor(s, 1);  s += __shfl_xor(s, 2);  s += __shfl_xor(s, 4);
  s += __shfl_xor(s, 8);  s += __shfl_xor(s, 16); s += __shfl_xor(s, 32);
  return s;
}

#define GLOAD16(g, l)                                                         \
  __builtin_amdgcn_global_load_lds(                                           \
      (const __attribute__((address_space(1))) void*)(g),                     \
      (__attribute__((address_space(3))) void*)(l), 16, 0, 0)

// ---------------------------------------------------------------------------
// Kernel 0 (fast path): X fp32 -> Xbf bf16.  grid 2048 x 256.
// ---------------------------------------------------------------------------
__global__ void convert_bf(const float* __restrict__ X,
                           unsigned short* __restrict__ Xbf) {
  long idx = (long)blockIdx.x * blockDim.x + threadIdx.x;
  const long stride = (long)gridDim.x * blockDim.x;
  const long nch = 134217728 / 8;
  for (long i = idx; i < nch; i += stride) {
    float4 f0 = ((const float4*)X)[i * 2];
    float4 f1 = ((const float4*)X)[i * 2 + 1];
    uint4 o;
    o.x = (unsigned)f2bf(f0.x) | ((unsigned)f2bf(f0.y) << 16);
    o.y = (unsigned)f2bf(f0.z) | ((unsigned)f2bf(f0.w) << 16);
    o.z = (unsigned)f2bf(f1.x) | ((unsigned)f2bf(f1.y) << 16);
    o.w = (unsigned)f2bf(f1.z) | ((unsigned)f2bf(f1.w) << 16);
    ((uint4*)Xbf)[i] = o;
  }
}

// ---------------------------------------------------------------------------
// Kernel 1 (fast path): Gram partials from bf16 X. grid = 3*nchunk x 512.
// pos = b%3: (0,0),(256,256),(0,256) 256x256 tiles; chunk = b/3 gets k-steps
// [4096*chunk/nchunk, 4096*(chunk+1)/nchunk).  LDS [c][k] swizzled, built by
// paired-row b32 pack writes.
// ---------------------------------------------------------------------------
__device__ __forceinline__ void stage_pack(const unsigned short* __restrict__ src,
                                           unsigned short* dst, int c0, int k) {
  uint4 a = *(const uint4*)src;          // row k,   cols c0..c0+7
  uint4 b = *(const uint4*)(src + 512);  // row k+1
  unsigned av[4] = {a.x, a.y, a.z, a.w}, bv[4] = {b.x, b.y, b.z, b.w};
  int k7 = (k & 7) * 2, khi = k >> 3;
  #pragma unroll
  for (int j = 0; j < 4; ++j) {
    int cA = c0 + 2 * j, cB = cA + 1;
    unsigned lo = (av[j] & 0xFFFFu) | (bv[j] << 16);
    unsigned hi = (av[j] >> 16) | (bv[j] & 0xFFFF0000u);
    int slA = khi ^ ((cA ^ (cA >> 3)) & 7);
    int slB = khi ^ ((cB ^ (cB >> 3)) & 7);
    *(unsigned*)((char*)dst + cA * 128 + slA * 16 + k7) = lo;
    *(unsigned*)((char*)dst + cB * 128 + slB * 16 + k7) = hi;
  }
}

__global__ __launch_bounds__(512, 2) void gram_bf(
    const unsigned short* __restrict__ Xbf, float* __restrict__ part,
    int nchunk) {
  __shared__ unsigned short As[256 * 64];
  __shared__ unsigned short Bs[256 * 64];
  const int b = blockIdx.x, pos = b % 3, chunk = b / 3;
  const int s0 = (int)((long)4096 * chunk / nchunk);
  const int s1 = (int)((long)4096 * (chunk + 1) / nchunk);
  const int ca = (pos == 1) ? 256 : 0;
  const int cb2 = (pos == 0) ? 0 : 256;
  const bool diag = (pos != 2);
  const int t = threadIdx.x, lane = t & 63, w = t >> 6;
  const int wr = w >> 2, wc = w & 3;

  f32x4 acc[8][4];
  const f32x4 zf = {0.f, 0.f, 0.f, 0.f};
  #pragma unroll
  for (int a = 0; a < 8; ++a)
    #pragma unroll
    for (int bb = 0; bb < 4; ++bb) acc[a][bb] = zf;

  const int c0 = (t & 31) * 8;   // relative col octet
  const int kp = t >> 5;         // 0..15

  for (int ks = s0; ks < s1; ++ks) {
    long rb = (long)ks * 64;
    #pragma unroll
    for (int it = 0; it < 2; ++it) {
      int k = it * 32 + kp * 2;
      long r = rb + k;
      stage_pack(Xbf + r * 512 + ca + c0, As, c0, k);
      if (!diag) stage_pack(Xbf + r * 512 + cb2 + c0, Bs, c0, k);
    }
    __syncthreads();
    const unsigned short* Bp = diag ? As : Bs;
    #pragma unroll
    for (int kk = 0; kk < 2; ++kk) {
      bf16x8 af[8], bfr[4];
      #pragma unroll
      for (int fm = 0; fm < 8; ++fm) {
        int row = wr * 128 + fm * 16 + (lane & 15);
        int slot = swz(row, kk * 4 + (lane >> 4));
        af[fm] = *(const bf16x8*)((const char*)As + row * 128 + slot * 16);
      }
      #pragma unroll
      for (int fn = 0; fn < 4; ++fn) {
        int row = wc * 64 + fn * 16 + (lane & 15);
        int slot = swz(row, kk * 4 + (lane >> 4));
        bfr[fn] = *(const bf16x8*)((const char*)Bp + row * 128 + slot * 16);
      }
      #pragma unroll
      for (int fm = 0; fm < 8; ++fm)
        #pragma unroll
        for (int fn = 0; fn < 4; ++fn)
          acc[fm][fn] = __builtin_amdgcn_mfma_f32_16x16x32_bf16(
              af[fm], bfr[fn], acc[fm][fn], 0, 0, 0);
    }
    __syncthreads();
  }
  float* out = part + (long)b * 65536;
  #pragma unroll
  for (int fm = 0; fm < 8; ++fm)
    #pragma unroll
    for (int fn = 0; fn < 4; ++fn)
      #pragma unroll
      for (int j = 0; j < 4; ++j) {
        int i  = wr * 128 + fm * 16 + (lane >> 4) * 4 + j;
        int jj = wc * 64 + fn * 16 + (lane & 15);
        out[i * 256 + jj] = acc[fm][fn][j];
      }
}

// ---------------------------------------------------------------------------
// Kernel 1b (fallback): Gram partials from fp32 X (round-1 version).
// ---------------------------------------------------------------------------
__global__ __launch_bounds__(512, 2) void gram_f32(
    const float* __restrict__ X, float* __restrict__ part, int nchunk) {
  __shared__ unsigned short As[256 * 64];
  __shared__ unsigned short Bs[256 * 64];
  const int b = blockIdx.x;
  const int pos = b % 3;
  const int chunk = b / 3;
  const int CR = 262144 / nchunk;
  const long r0 = (long)chunk * CR;
  const int ca = (pos == 1) ? 256 : 0;
  const int cb = (pos == 0) ? 0 : 256;
  const bool diag = (pos != 2);
  const int t = threadIdx.x, lane = t & 63, w = t >> 6;
  const int wr = w >> 2, wc = w & 3;

  f32x4 acc[8][4];
  const f32x4 zf = {0.f, 0.f, 0.f, 0.f};
  #pragma unroll
  for (int a = 0; a < 8; ++a)
    #pragma unroll
    for (int bb = 0; bb < 4; ++bb) acc[a][bb] = zf;

  const int c_oct = t & 31, msub = t >> 5;

  for (int ks = 0; ks < CR; ks += 64) {
    #pragma unroll
    for (int it = 0; it < 4; ++it) {
      int m = msub + 16 * it;
      long row = r0 + ks + m;
      const float4* sa = (const float4*)(X + row * 512 + ca + c_oct * 8);
      float4 a0 = sa[0], a1 = sa[1];
      {
        float v[8] = {a0.x, a0.y, a0.z, a0.w, a1.x, a1.y, a1.z, a1.w};
        #pragma unroll
        for (int s = 0; s < 8; ++s) {
          int c = c_oct * 8 + s;
          int off = c * 128 + ((2 * m) ^ (((c ^ (c >> 3)) & 7) << 4));
          *(unsigned short*)((char*)As + off) = f2bf(v[s]);
        }
      }
      if (!diag) {
        const float4* sb = (const float4*)(X + row * 512 + cb + c_oct * 8);
        float4 b0 = sb[0], b1 = sb[1];
        float v[8] = {b0.x, b0.y, b0.z, b0.w, b1.x, b1.y, b1.z, b1.w};
        #pragma unroll
        for (int s = 0; s < 8; ++s) {
          int c = c_oct * 8 + s;
          int off = c * 128 + ((2 * m) ^ (((c ^ (c >> 3)) & 7) << 4));
          *(unsigned short*)((char*)Bs + off) = f2bf(v[s]);
        }
      }
    }
    __syncthreads();
    const unsigned short* Bp = diag ? As : Bs;
    #pragma unroll
    for (int kk = 0; kk < 2; ++kk) {
      bf16x8 af[8], bfr[4];
      #pragma unroll
      for (int fm = 0; fm < 8; ++fm) {
        int row = wr * 128 + fm * 16 + (lane & 15);
        int slot = swz(row, kk * 4 + (lane >> 4));
        af[fm] = *(const bf16x8*)((const char*)As + row * 128 + slot * 16);
      }
      #pragma unroll
      for (int fn = 0; fn < 4; ++fn) {
        int row = wc * 64 + fn * 16 + (lane & 15);
        int slot = swz(row, kk * 4 + (lane >> 4));
        bfr[fn] = *(const bf16x8*)((const char*)Bp + row * 128 + slot * 16);
      }
      #pragma unroll
      for (int fm = 0; fm < 8; ++fm)
        #pragma unroll
        for (int fn = 0; fn < 4; ++fn)
          acc[fm][fn] = __builtin_amdgcn_mfma_f32_16x16x32_bf16(
              af[fm], bfr[fn], acc[fm][fn], 0, 0, 0);
    }
    __syncthreads();
  }
  float* out = part + (long)b * 65536;
  #pragma unroll
  for (int fm = 0; fm < 8; ++fm)
    #pragma unroll
    for (int fn = 0; fn < 4; ++fn)
      #pragma unroll
      for (int j = 0; j < 4; ++j) {
        int i  = wr * 128 + fm * 16 + (lane >> 4) * 4 + j;
        int jj = wc * 64 + fn * 16 + (lane & 15);
        out[i * 256 + jj] = acc[fm][fn][j];
      }
}

// ---------------------------------------------------------------------------
// Kernel 2: reduce partials -> full symmetric G [512][512] fp32. grid 768x256
// ---------------------------------------------------------------------------
__global__ void gram_reduce(const float* __restrict__ part,
                            float* __restrict__ G, int nchunk) {
  int idx = blockIdx.x * 256 + threadIdx.x;   // < 196608
  int pos = idx >> 16;
  int e = idx & 65535;
  float s = 0.f;
  for (int ch = 0; ch < nchunk; ++ch)
    s += part[(long)(ch * 3 + pos) * 65536 + e];
  int i = e >> 8, j = e & 255;
  if (pos == 0) {
    G[i * 512 + j] = s;
  } else if (pos == 1) {
    G[(256 + i) * 512 + 256 + j] = s;
  } else {
    G[i * 512 + 256 + j] = s;
    G[(256 + j) * 512 + i] = s;
  }
}

// ---------------------------------------------------------------------------
// Kernel 3: factor 128x128 diagonal block at (c0,c0) of G in place (lower L).
// ---------------------------------------------------------------------------
__global__ void chol_diag(float* __restrict__ G, int c0) {
  __shared__ float P[128][129];
  int t = threadIdx.x;
  for (int idx = t; idx < 128 * 128; idx += 512) {
    int i = idx >> 7, j = idx & 127;
    float v = G[(long)(c0 + i) * 512 + c0 + j];
    if (i == j) v += EPSJ;
    P[i][j] = v;
  }
  __syncthreads();
  int lane = t & 63, w = t >> 6;
  for (int sp = 0; sp < 4; ++sp) {
    int b0 = sp * 32;
    if (w == 0) {
      float r[32];
      #pragma unroll
      for (int k = 0; k < 32; ++k) r[k] = (lane < 32) ? P[b0 + lane][b0 + k] : 0.f;
      #pragma unroll
      for (int j = 0; j < 32; ++j) {
        float d = sqrtf(__shfl(r[j], j));
        if (lane == j) r[j] = d;
        else if (lane > j && lane < 32) r[j] = r[j] / d;
        float rj = r[j];
        #pragma unroll
        for (int k = j + 1; k < 32; ++k) {
          float Lkj = __shfl(rj, k);
          if (lane > j && lane < 32) r[k] -= rj * Lkj;
        }
      }
      #pragma unroll
      for (int k = 0; k < 32; ++k) if (lane < 32) P[b0 + lane][b0 + k] = r[k];
    }
    __syncthreads();
    int nb = 128 - (b0 + 32);
    if (nb > 0) {
      if (t < nb) {
        int rr = b0 + 32 + t;
        float x[32];
        #pragma unroll
        for (int j = 0; j < 32; ++j) x[j] = P[rr][b0 + j];
        #pragma unroll
        for (int j = 0; j < 32; ++j) {
          float xj = x[j] / P[b0 + j][b0 + j];
          x[j] = xj;
          #pragma unroll
          for (int k2 = j + 1; k2 < 32; ++k2) x[k2] -= xj * P[b0 + k2][b0 + j];
        }
        #pragma unroll
        for (int j = 0; j < 32; ++j) P[rr][b0 + j] = x[j];
      }
      __syncthreads();
      int total = nb * nb;
      for (int idx = t; idx < total; idx += 512) {
        int i = b0 + 32 + idx / nb, k = b0 + 32 + idx % nb;
        float s = P[i][k];
        #pragma unroll
        for (int j = 0; j < 32; ++j) s -= P[i][b0 + j] * P[k][b0 + j];
        P[i][k] = s;
      }
      __syncthreads();
    }
  }
  for (int idx = t; idx < 128 * 128; idx += 512) {
    int i = idx >> 7, j = idx & 127;
    G[(long)(c0 + i) * 512 + c0 + j] = P[i][j];
  }
}

// ---------------------------------------------------------------------------
// Kernel 4: panel solve (wave-per-row forward substitution). grid R/4 x 256.
// ---------------------------------------------------------------------------
__global__ void chol_solve(float* __restrict__ G, int p) {
  int c0 = 128 * p;
  int row0 = c0 + 128;
  int w = threadIdx.x >> 6, lane = threadIdx.x & 63;
  long r = row0 + blockIdx.x * 4 + w;
  float x[2];
  x[0] = G[r * 512 + c0 + lane];
  x[1] = G[r * 512 + c0 + 64 + lane];
  #pragma unroll
  for (int q = 0; q < 2; ++q) {
    for (int ii = 0; ii < 64; ++ii) {
      int i = q * 64 + ii;
      const float* Lrow = G + (long)(c0 + i) * 512 + c0;
      float s = 0.f;
      if (q == 1) s += x[0] * Lrow[lane];
      s += (lane < ii) ? x[q] * Lrow[q * 64 + lane] : 0.f;
      s = wred(s);
      float ai = __shfl(x[q], ii);
      float xi = (ai - s) / Lrow[i];
      if (lane == ii) x[q] = xi;
    }
  }
  G[r * 512 + c0 + lane] = x[0];
  G[r * 512 + c0 + 64 + lane] = x[1];
}

// ---------------------------------------------------------------------------
// Kernel 5: SYRK trailing update A22 -= L21 L21^T, 64x64 lower tiles, fp32.
// ---------------------------------------------------------------------------
__global__ void chol_syrk(float* __restrict__ G, int t0) {
  int id = blockIdx.x;
  int ti = 0;
  while ((ti + 1) * (ti + 2) / 2 <= id) ++ti;
  int tj = id - ti * (ti + 1) / 2;
  __shared__ float As2[64][130], Bs2[64][130];
  int t = threadIdx.x;
  int c0 = t0 - 128;
  for (int idx = t; idx < 64 * 128; idx += 256) {
    int i = idx >> 7, j = idx & 127;
    As2[i][j] = G[(long)(t0 + 64 * ti + i) * 512 + c0 + j];
    Bs2[i][j] = G[(long)(t0 + 64 * tj + i) * 512 + c0 + j];
  }
  __syncthreads();
  int tr = (t >> 4) * 4, tc = (t & 15) * 4;
  float cacc[4][4];
  #pragma unroll
  for (int u = 0; u < 4; ++u)
    #pragma unroll
    for (int v = 0; v < 4; ++v) cacc[u][v] = 0.f;
  for (int k = 0; k < 128; ++k) {
    float a4[4], b4[4];
    #pragma unroll
    for (int u = 0; u < 4; ++u) { a4[u] = As2[tr + u][k]; b4[u] = Bs2[tc + u][k]; }
    #pragma unroll
    for (int u = 0; u < 4; ++u)
      #pragma unroll
      for (int v = 0; v < 4; ++v) cacc[u][v] += a4[u] * b4[v];
  }
  #pragma unroll
  for (int u = 0; u < 4; ++u)
    #pragma unroll
    for (int v = 0; v < 4; ++v)
      G[(long)(t0 + 64 * ti + tr + u) * 512 + t0 + 64 * tj + tc + v] -= cacc[u][v];
}

// ---------------------------------------------------------------------------
// Kernel 6: triangular inverse, wave-per-column. SWZ: bake the ymm2 B-side
// LDS slot swizzle into Wt's global layout so ymm2 stages with identity
// global_load_lds.  Wt[n][k-slot-swizzled] = sqrt(512)*L^{-1}[n][k] bf16.
// ---------------------------------------------------------------------------
template <bool SWZ>
__global__ void tri_inv(const float* __restrict__ G,
                        unsigned short* __restrict__ Wt) {
  int w = threadIdx.x >> 6, lane = threadIdx.x & 63;
  int c = blockIdx.x * 4 + w;
  float v8[8];
  #pragma unroll
  for (int q = 0; q < 8; ++q) v8[q] = 0.f;
  #pragma unroll
  for (int q = 0; q < 8; ++q) {
    for (int ii = 0; ii < 64; ++ii) {
      int i = q * 64 + ii;
      const float* Lrow = G + (long)i * 512;
      float s = 0.f;
      #pragma unroll
      for (int qq = 0; qq < 8; ++qq) {
        if (qq < q) s += v8[qq] * Lrow[qq * 64 + lane];
      }
      s += (lane < ii) ? v8[q] * Lrow[q * 64 + lane] : 0.f;
      s = wred(s);
      float xi = (((i == c) ? 1.f : 0.f) - s) / Lrow[i];
      if (lane == ii) v8[q] = xi;
    }
  }
  if (SWZ) {
    int ko = (c >> 3) & 7, jj = c & 7, cb = c & ~63;
    #pragma unroll
    for (int q = 0; q < 8; ++q) {
      int n = q * 64 + lane;
      int sl = ko ^ ((n ^ (n >> 3)) & 7);
      Wt[(long)n * 512 + cb + sl * 8 + jj] = f2bf(SQRTD * v8[q]);
    }
  } else {
    #pragma unroll
    for (int q = 0; q < 8; ++q) {
      int i = q * 64 + lane;
      Wt[(long)i * 512 + c] = f2bf(SQRTD * v8[q]);
    }
  }
}

// ---------------------------------------------------------------------------
// Kernel 7 (fast path): Y = Xbf @ W via global_load_lds staging, dbuf 2-phase.
// grid (4 n, 2048 m) x 256 — n fastest so X rows are L2/L3-shared.
// A source addresses inverse-swizzled (LDS dest linear); B pre-swizzled in Wt.
// ---------------------------------------------------------------------------
__global__ __launch_bounds__(256, 2) void ymm2(
    const unsigned short* __restrict__ Xbf,
    const unsigned short* __restrict__ Wt, float* __restrict__ Y) {
  __shared__ unsigned short As[2][128 * 64];
  __shared__ unsigned short Bs[2][128 * 64];
  const int t = threadIdx.x, lane = t & 63, w = t >> 6;
  const long m0 = (long)blockIdx.y * 128;
  const int n0 = blockIdx.x * 128;
  const int wm = (w >> 1) * 64, wn = (w & 1) * 64;
  const int lrow = lane >> 3, lslot = lane & 7;
  f32x4 acc[4][4];
  const f32x4 zf = {0.f, 0.f, 0.f, 0.f};
  #pragma unroll
  for (int a = 0; a < 4; ++a)
    #pragma unroll
    for (int bq = 0; bq < 4; ++bq) acc[a][bq] = zf;

  auto stage = [&](int buf, int k0) {
    #pragma unroll
    for (int j = 0; j < 4; ++j) {
      int row = (w * 4 + j) * 8 + lrow;
      const unsigned short* sA =
          Xbf + (m0 + row) * 512 + k0 + swz(row, lslot) * 8;
      const unsigned short* sB =
          Wt + (long)(n0 + row) * 512 + k0 + lslot * 8;
      GLOAD16(sA, &As[buf][(w * 4 + j) * 512]);
      GLOAD16(sB, &Bs[buf][(w * 4 + j) * 512]);
    }
  };
  auto compute = [&](int buf) {
    #pragma unroll
    for (int kk = 0; kk < 2; ++kk) {
      bf16x8 af[4], bfr[4];
      #pragma unroll
      for (int fm = 0; fm < 4; ++fm) {
        int row = wm + fm * 16 + (lane & 15);
        af[fm] = *(const bf16x8*)((const char*)As[buf] + row * 128 +
                                  swz(row, kk * 4 + (lane >> 4)) * 16);
      }
      #pragma unroll
      for (int fn = 0; fn < 4; ++fn) {
        int row = wn + fn * 16 + (lane & 15);
        bfr[fn] = *(const bf16x8*)((const char*)Bs[buf] + row * 128 +
                                   swz(row, kk * 4 + (lane >> 4)) * 16);
      }
      #pragma unroll
      for (int fm = 0; fm < 4; ++fm)
        #pragma unroll
        for (int fn = 0; fn < 4; ++fn)
          acc[fm][fn] = __builtin_amdgcn_mfma_f32_16x16x32_bf16(
              af[fm], bfr[fn], acc[fm][fn], 0, 0, 0);
    }
  };

  stage(0, 0);
  __syncthreads();
  int cur = 0;
  #pragma unroll 1
  for (int kt = 0; kt < 7; ++kt) {
    stage(cur ^ 1, (kt + 1) * 64);
    compute(cur);
    __syncthreads();
    cur ^= 1;
  }
  compute(cur);

  #pragma unroll
  for (int fm = 0; fm < 4; ++fm)
    #pragma unroll
    for (int fn = 0; fn < 4; ++fn)
      #pragma unroll
      for (int j = 0; j < 4; ++j) {
        long row = m0 + wm + fm * 16 + (lane >> 4) * 4 + j;
        int col = n0 + wn + fn * 16 + (lane & 15);
        Y[row * 512 + col] = acc[fm][fn][j];
      }
}

// ---------------------------------------------------------------------------
// Kernel 7b (fallback): round-1 ymm, fp32 X reg-staged.
// ---------------------------------------------------------------------------
__global__ __launch_bounds__(256) void ymm_v1(const float* __restrict__ X,
                                              const unsigned short* __restrict__ Wt,
                                              float* __restrict__ Y) {
  __shared__ unsigned short As[128 * 64];
  __shared__ unsigned short Bs[128 * 64];
  const int t = threadIdx.x, lane = t & 63, w = t >> 6;
  const long m0 = (long)blockIdx.x * 128;
  const int n0 = blockIdx.y * 128;
  const int wm = (w >> 1) * 64, wn = (w & 1) * 64;
  f32x4 acc[4][4];
  const f32x4 zf = {0.f, 0.f, 0.f, 0.f};
  #pragma unroll
  for (int a = 0; a < 4; ++a)
    #pragma unroll
    for (int bq = 0; bq < 4; ++bq) acc[a][bq] = zf;
  const int ko = t & 7, mrow = t >> 3;

  for (int k0 = 0; k0 < 512; k0 += 64) {
    #pragma unroll
    for (int it = 0; it < 4; ++it) {
      int m = mrow + 32 * it;
      const float4* src = (const float4*)(X + (m0 + m) * 512 + k0 + ko * 8);
      float4 f0 = src[0], f1 = src[1];
      unsigned p0 = (unsigned)f2bf(f0.x) | ((unsigned)f2bf(f0.y) << 16);
      unsigned p1 = (unsigned)f2bf(f0.z) | ((unsigned)f2bf(f0.w) << 16);
      unsigned p2 = (unsigned)f2bf(f1.x) | ((unsigned)f2bf(f1.y) << 16);
      unsigned p3 = (unsigned)f2bf(f1.z) | ((unsigned)f2bf(f1.w) << 16);
      int slot = swz(m, ko);
      *(uint4*)((char*)As + m * 128 + slot * 16) = make_uint4(p0, p1, p2, p3);
    }
    #pragma unroll
    for (int it = 0; it < 4; ++it) {
      int n = mrow + 32 * it;
      uint4 raw = *(const uint4*)(Wt + (long)(n0 + n) * 512 + k0 + ko * 8);
      int slot = swz(n, ko);
      *(uint4*)((char*)Bs + n * 128 + slot * 16) = raw;
    }
    __syncthreads();
    #pragma unroll
    for (int kk = 0; kk < 2; ++kk) {
      bf16x8 af[4], bfr[4];
      #pragma unroll
      for (int fm = 0; fm < 4; ++fm) {
        int row = wm + fm * 16 + (lane & 15);
        af[fm] = *(const bf16x8*)((const char*)As + row * 128 +
                                  swz(row, kk * 4 + (lane >> 4)) * 16);
      }
      #pragma unroll
      for (int fn = 0; fn < 4; ++fn) {
        int row = wn + fn * 16 + (lane & 15);
        bfr[fn] = *(const bf16x8*)((const char*)Bs + row * 128 +
                                   swz(row, kk * 4 + (lane >> 4)) * 16);
      }
      #pragma unroll
      for (int fm = 0; fm < 4; ++fm)
        #pragma unroll
        for (int fn = 0; fn < 4; ++fn)
          acc[fm][fn] = __builtin_amdgcn_mfma_f32_16x16x32_bf16(
              af[fm], bfr[fn], acc[fm][fn], 0, 0, 0);
    }
    __syncthreads();
  }
  #pragma unroll
  for (int fm = 0; fm < 4; ++fm)
    #pragma unroll
    for (int fn = 0; fn < 4; ++fn)
      #pragma unroll
      for (int j = 0; j < 4; ++j) {
        long row = m0 + wm + fm * 16 + (lane >> 4) * 4 + j;
        int col = n0 + wn + fn * 16 + (lane & 15);
        Y[row * 512 + col] = acc[fm][fn][j];
      }
}

// ---------------------------------------------------------------------------
static void chol_chain(float* G, hipStream_t stream) {
  for (int p = 0; p < 4; ++p) {
    chol_diag<<<1, 512, 0, stream>>>(G, 128 * p);
    if (p < 3) {
      int row0 = 128 * (p + 1);
      chol_solve<<<(512 - row0) / 4, 256, 0, stream>>>(G, p);
      int nt = (512 - row0) / 64;
      chol_syrk<<<nt * (nt + 1) / 2, 256, 0, stream>>>(G, row0);
    }
  }
}

extern "C" void kernel_launch(void* const* d_in, const int* in_sizes, int n_in,
                              void* d_out, int out_size, void* d_ws, size_t ws_size,
                              hipStream_t stream) {
  const float* X = (const float*)d_in[0];
  float* Y = (float*)d_out;
  char* ws = (char*)d_ws;
  float* G = (float*)ws;                                     // 1 MiB fp32
  unsigned short* Wt = (unsigned short*)(ws + (1 << 20));    // 512 KiB bf16
  char* wsp = ws + (1 << 20) + (1 << 19);

  const int NCH_FAST = 85;
  size_t part_bytes = (size_t)NCH_FAST * 3 * 65536 * 4;      // 66.8 MB
  size_t xbf_off = (size_t)(1 << 20) + (1 << 19) + part_bytes;
  size_t need = xbf_off + (size_t)134217728 * 2;             // + 256 MiB

  if (ws_size >= need) {
    float* part = (float*)wsp;
    unsigned short* Xbf = (unsigned short*)(ws + xbf_off);
    convert_bf<<<2048, 256, 0, stream>>>(X, Xbf);
    gram_bf<<<3 * NCH_FAST, 512, 0, stream>>>(Xbf, part, NCH_FAST);
    gram_reduce<<<768, 256, 0, stream>>>(part, G, NCH_FAST);
    chol_chain(G, stream);
    tri_inv<true><<<128, 256, 0, stream>>>(G, Wt);
    ymm2<<<dim3(4, 2048), 256, 0, stream>>>(Xbf, Wt, Y);
  } else {
    float* part = (float*)wsp;
    size_t fixed = (size_t)(1 << 20) + (1 << 19);
    int nchunk = 64;
    while (nchunk > 1 && fixed + (size_t)nchunk * 3 * 65536 * 4 > ws_size)
      nchunk >>= 1;
    gram_f32<<<3 * nchunk, 512, 0, stream>>>(X, part, nchunk);
    gram_reduce<<<768, 256, 0, stream>>>(part, G, nchunk);
    chol_chain(G, stream);
    tri_inv<false><<<128, 256, 0, stream>>>(G, Wt);
    ymm_v1<<<dim3(2048, 4), 256, 0, stream>>>(X, Wt, Y);
  }
}